// Round 9
// baseline (295.114 us; speedup 1.0000x reference)
//
#include <hip/hip_runtime.h>
#include <hip/hip_bf16.h>

#define NKEYS  100000
#define NCH    192
#define CHK    576             // 9 tiles of 64 keys
#define TPC    9               // tiles per chunk
#define KPAD   (NCH * CHK)     // 110592 (3.8% pad buys grid = exactly 3 blocks/CU)
#define NTILE  (KPAD / 64)     // 1728
#define BQ     1024
#define EPS_F  1e-6f
#define NCAND  (NCH * 3)       // 576 candidates per row
#define BIGF   1e30f

typedef __attribute__((ext_vector_type(8))) short bf16x8;
typedef __attribute__((ext_vector_type(4))) float f32x4;

__device__ __forceinline__ void gl_lds16(const uint4* g, uint4* l) {
    __builtin_amdgcn_global_load_lds((const __attribute__((address_space(1))) void*)g,
                                     (__attribute__((address_space(3))) void*)l, 16, 0, 0);
}
__device__ __forceinline__ unsigned umn(unsigned a, unsigned b) { return a < b ? a : b; }
__device__ __forceinline__ unsigned umx(unsigned a, unsigned b) { return a > b ? a : b; }
__device__ __forceinline__ ushort bf16bits(float v) {
    __hip_bfloat16 h = __float2bfloat16(v);
    return *(ushort*)&h;
}

__device__ __forceinline__ void ins3u(unsigned (&m)[3], unsigned u) {
    unsigned v1 = umn(m[2], u);
    m[2] = umx(m[1], v1);
    unsigned v2 = umn(m[1], v1);
    m[1] = umx(m[0], v2);
    m[0] = umn(m[0], v2);
}

__device__ __forceinline__ void ins5(float (&d)[5], int (&ix)[5], float nd, int ni) {
    if (nd < d[4]) {
        d[4] = nd; ix[4] = ni;
#pragma unroll
        for (int p = 4; p > 0; --p) {
            if (d[p] < d[p - 1]) {
                float td = d[p]; d[p] = d[p - 1]; d[p - 1] = td;
                int   ti = ix[p]; ix[p] = ix[p - 1]; ix[p - 1] = ti;
            }
        }
    }
}

// ---------- key preprocessing: fragment-major bf16 image + kk + (-kk/2) ----------
__global__ __launch_bounds__(256)
void cvt_keys(const float* __restrict__ keys, uint4* __restrict__ img,
              float* __restrict__ kk, float* __restrict__ khalf) {
    const int tid = threadIdx.x;
    const int r = tid >> 2, s = tid & 3;
    const int tile = blockIdx.x;
    const int n = tile * 64 + r;
    const int ct = r >> 4, l15 = r & 15;
    const bool live = (n < NKEYS);
    const float* kp = keys + (size_t)n * 128 + s * 32;
    float ss = 0.f;
    uint4 out[4];
#pragma unroll
    for (int q = 0; q < 4; ++q) {
        float4 a = make_float4(0.f, 0.f, 0.f, 0.f), b = a;
        if (live) { a = *(const float4*)(kp + q * 8); b = *(const float4*)(kp + q * 8 + 4); }
        ss += a.x * a.x + a.y * a.y + a.z * a.z + a.w * a.w
            + b.x * b.x + b.y * b.y + b.z * b.z + b.w * b.w;
        float v[8] = {a.x, a.y, a.z, a.w, b.x, b.y, b.z, b.w};
        ushort h[8];
#pragma unroll
        for (int j = 0; j < 8; ++j) h[j] = bf16bits(v[j]);
        out[q] = make_uint4((uint)h[0] | ((uint)h[1] << 16), (uint)h[2] | ((uint)h[3] << 16),
                            (uint)h[4] | ((uint)h[5] << 16), (uint)h[6] | ((uint)h[7] << 16));
    }
    ss += __shfl_xor(ss, 1, 64);
    ss += __shfl_xor(ss, 2, 64);
    if (s == 0) {
        kk[n]    = live ? ss : BIGF;
        khalf[n] = live ? -0.5f * ss : -BIGF;
    }
#pragma unroll
    for (int q = 0; q < 4; ++q)
        img[(size_t)tile * 1024 + ((ct * 4 + s) * 4 + q) * 16 + l15] = out[q];
}

// ---------- fused compress prep: query split-A (blocks 0..1023) + W1 K-tripled image ----------
__global__ __launch_bounds__(256)
void prep(const float* __restrict__ A, ushort* __restrict__ Ax,
          const float* __restrict__ W, uint4* __restrict__ Wimg) {
    const int b = blockIdx.x;
    if (b < 1024) {
        // query row -> [xh | xl | xh] bf16, K=1024
        const int row = b;
        const int i = threadIdx.x * 4;
        float4 v = *(const float4*)&A[(size_t)row * 1024 + i];
        float x[4] = {v.x, v.y, v.z, v.w};
        ushort h[4], l[4];
#pragma unroll
        for (int j = 0; j < 4; ++j) {
            __hip_bfloat16 hb = __float2bfloat16(x[j]);
            h[j] = *(ushort*)&hb;
            l[j] = bf16bits(x[j] - __bfloat162float(hb));
        }
        ushort* o = Ax + (size_t)row * 3072;
        *(ushort4*)&o[i]        = make_ushort4(h[0], h[1], h[2], h[3]);
        *(ushort4*)&o[1024 + i] = make_ushort4(l[0], l[1], l[2], l[3]);
        *(ushort4*)&o[2048 + i] = make_ushort4(h[0], h[1], h[2], h[3]);
    } else {
        // W1 [1024,512] -> fragment-major bf16 image, K-tripled [wh; wh; wl]
        const int idx = b - 1024;          // 0..383
        const int ctile = idx / 48, p = idx % 48;
        const int part = p >> 4, psrc = p & 15;
#pragma unroll
        for (int it = 0; it < 2; ++it) {
            int c = it * 256 + threadIdx.x;
            int l15 = c & 15, quad = (c >> 4) & 3, s = (c >> 6) & 1, ct = c >> 7;
            int n = ctile * 64 + ct * 16 + l15;
            int k = psrc * 64 + s * 32 + quad * 8;
            ushort h[8];
#pragma unroll
            for (int j = 0; j < 8; ++j) {
                float w = W[(size_t)(k + j) * 512 + n];
                __hip_bfloat16 hb = __float2bfloat16(w);
                if (part < 2) h[j] = *(ushort*)&hb;
                else h[j] = bf16bits(w - __bfloat162float(hb));
            }
            Wimg[((size_t)ctile * 48 + p) * 512 + c] =
                make_uint4((uint)h[0] | ((uint)h[1] << 16), (uint)h[2] | ((uint)h[3] << 16),
                           (uint)h[4] | ((uint)h[5] << 16), (uint)h[6] | ((uint)h[7] << 16));
        }
    }
}

// ---------- bf16-MFMA split-K partial GEMM: P[z] = A@W over panel slab ----------
__global__ __launch_bounds__(256)
void bgemm_part(const ushort* __restrict__ Abf, const uint4* __restrict__ Wimg,
                float* __restrict__ P, int M, int N, int K, int ppz) {
    __shared__ uint4 pan[2][512];
    const int tid = threadIdx.x;
    const int wv = tid >> 6, ln = tid & 63;
    const int quad = ln >> 4, l15 = ln & 15;
    const int n0 = blockIdx.x * 64;
    const int m0 = blockIdx.y * 128 + wv * 32;
    const int ctile = blockIdx.x, npanT = K >> 6;
    const int p0 = blockIdx.z * ppz;
    f32x4 acc[2][4];
#pragma unroll
    for (int s = 0; s < 2; ++s)
#pragma unroll
        for (int c = 0; c < 4; ++c) acc[s][c] = (f32x4){0.f, 0.f, 0.f, 0.f};

#pragma unroll
    for (int it = 0; it < 2; ++it)
        gl_lds16(&Wimg[((size_t)ctile * npanT + p0) * 512 + it * 256 + wv * 64 + ln],
                 &pan[0][it * 256 + wv * 64]);
    __syncthreads();

    for (int pp = 0; pp < ppz; ++pp) {
        const int p = p0 + pp;
        const int b = pp & 1;
        if (pp + 1 < ppz) {
#pragma unroll
            for (int it = 0; it < 2; ++it)
                gl_lds16(&Wimg[((size_t)ctile * npanT + p + 1) * 512 + it * 256 + wv * 64 + ln],
                         &pan[b ^ 1][it * 256 + wv * 64]);
        }
        const ushort* arow = Abf + (size_t)(m0 + l15) * K + p * 64 + quad * 8;
        bf16x8 afA[2], afB[2];
#pragma unroll
        for (int s = 0; s < 2; ++s) {
            afA[s] = *(const bf16x8*)(arow + s * 32);
            afB[s] = *(const bf16x8*)(arow + (size_t)16 * K + s * 32);
        }
#pragma unroll
        for (int ct = 0; ct < 4; ++ct)
#pragma unroll
            for (int s = 0; s < 2; ++s) {
                bf16x8 bfr = *(const bf16x8*)&pan[b][((ct * 2 + s) * 4 + quad) * 16 + l15];
                acc[0][ct] = __builtin_amdgcn_mfma_f32_16x16x32_bf16(afA[s], bfr, acc[0][ct], 0, 0, 0);
                acc[1][ct] = __builtin_amdgcn_mfma_f32_16x16x32_bf16(afB[s], bfr, acc[1][ct], 0, 0, 0);
            }
        __syncthreads();
    }

    P += (size_t)blockIdx.z * M * N;
#pragma unroll
    for (int ct = 0; ct < 4; ++ct) {
        const int col = n0 + ct * 16 + l15;
#pragma unroll
        for (int set = 0; set < 2; ++set)
#pragma unroll
            for (int r = 0; r < 4; ++r)
                P[(size_t)(m0 + set * 16 + quad * 4 + r) * N + col] = acc[set][ct][r];
    }
}

// ---------- split-K f32 GEMM; A-side fuses NP-partial reduce+bias+relu ----------
template <int NP>
__global__ __launch_bounds__(256)
void sgemm_part(const float* __restrict__ A, const float* __restrict__ abias,
                const float* __restrict__ W, float* __restrict__ P,
                int M, int N, int K, int kslice, int MNpart) {
    __shared__ float As[16][68];
    __shared__ float Bs[16][64];
    const int tid = threadIdx.x;
    const int tx = tid & 15, ty = tid >> 4;
    const int m0 = blockIdx.y * 64, n0 = blockIdx.x * 64;
    const int kb = blockIdx.z * kslice, ke = kb + kslice;
    float acc[4][4] = {};
    for (int k0 = kb; k0 < ke; k0 += 16) {
        {
            int m = tid >> 2, k4 = (tid & 3) * 4;
            const float* ap = &A[(size_t)(m0 + m) * K + k0 + k4];
            float4 a = *(const float4*)ap;
            if (NP > 0) {
#pragma unroll
                for (int z = 1; z < NP; ++z) {
                    float4 v = *(const float4*)(ap + (size_t)z * MNpart);
                    a.x += v.x; a.y += v.y; a.z += v.z; a.w += v.w;
                }
                float4 b = *(const float4*)&abias[k0 + k4];
                a.x = fmaxf(a.x + b.x, 0.f); a.y = fmaxf(a.y + b.y, 0.f);
                a.z = fmaxf(a.z + b.z, 0.f); a.w = fmaxf(a.w + b.w, 0.f);
            }
            As[k4 + 0][m] = a.x; As[k4 + 1][m] = a.y;
            As[k4 + 2][m] = a.z; As[k4 + 3][m] = a.w;
        }
        {
            int k = tid >> 4, n4 = (tid & 15) * 4;
            *(float4*)&Bs[k][n4] = *(const float4*)&W[(size_t)(k0 + k) * N + n0 + n4];
        }
        __syncthreads();
#pragma unroll
        for (int kkk = 0; kkk < 16; ++kkk) {
            float4 a4 = *(const float4*)&As[kkk][ty * 4];
            float4 b4 = *(const float4*)&Bs[kkk][tx * 4];
            float av[4] = {a4.x, a4.y, a4.z, a4.w};
            float bv[4] = {b4.x, b4.y, b4.z, b4.w};
#pragma unroll
            for (int i = 0; i < 4; ++i)
#pragma unroll
                for (int j = 0; j < 4; ++j)
                    acc[i][j] = fmaf(av[i], bv[j], acc[i][j]);
        }
        __syncthreads();
    }
    P += (size_t)blockIdx.z * M * N;
#pragma unroll
    for (int i = 0; i < 4; ++i)
        *(float4*)&P[(size_t)(m0 + ty * 4 + i) * N + n0 + tx * 4] =
            make_float4(acc[i][0], acc[i][1], acc[i][2], acc[i][3]);
}

// ---------- final compress layer: 4-partial reduce + bias -> cq f32, qbf bf16, qq rowsq ----------
__global__ __launch_bounds__(128)
void final_row(const float* __restrict__ P, const float* __restrict__ bias,
               float* __restrict__ cq, ushort* __restrict__ qbf,
               float* __restrict__ qq) {
    __shared__ float red[2];
    const int row = blockIdx.x, c = threadIdx.x;
    float v = 0.f;
#pragma unroll
    for (int z = 0; z < 4; ++z) v += P[(size_t)z * (BQ * 128) + row * 128 + c];
    v += bias[c];
    cq[(size_t)row * 128 + c] = v;
    qbf[(size_t)row * 128 + c] = bf16bits(v);
    float s = v * v;
#pragma unroll
    for (int off = 32; off > 0; off >>= 1) s += __shfl_down(s, off, 64);
    if ((c & 63) == 0) red[c >> 6] = s;
    __syncthreads();
    if (c == 0) qq[row] = red[0] + red[1];
}

// ---------- decompress weights -> fragment-major bf16 images (one fused dispatch) ----------
__device__ __forceinline__ void wT_panel(const float* __restrict__ W, uint4* __restrict__ Wimg,
                                         int K, int N, int ctile, int p) {
    const int npan = K >> 6;
#pragma unroll
    for (int it = 0; it < 2; ++it) {
        int c = it * 256 + threadIdx.x;
        int l15 = c & 15, quad = (c >> 4) & 3, s = (c >> 6) & 1, ct = c >> 7;
        int n = ctile * 64 + ct * 16 + l15;
        int k = p * 64 + s * 32 + quad * 8;
        ushort h[8];
#pragma unroll
        for (int j = 0; j < 8; ++j) h[j] = bf16bits(W[(size_t)(k + j) * N + n]);
        Wimg[((size_t)ctile * npan + p) * 512 + c] =
            make_uint4((uint)h[0] | ((uint)h[1] << 16), (uint)h[2] | ((uint)h[3] << 16),
                       (uint)h[4] | ((uint)h[5] << 16), (uint)h[6] | ((uint)h[7] << 16));
    }
}

__global__ __launch_bounds__(256)
void cvt_wT_all(const float* __restrict__ W1, const float* __restrict__ W2,
                const float* __restrict__ W3, uint4* __restrict__ I1,
                uint4* __restrict__ I2, uint4* __restrict__ I3) {
    int b = blockIdx.x;
    if (b < 8)       { wT_panel(W1, I1, 128, 256,  b >> 1, b & 1); }
    else if (b < 40) { b -= 8;  wT_panel(W2, I2, 256, 512,  b >> 2, b & 3); }
    else             { b -= 40; wT_panel(W3, I3, 512, 1024, b >> 3, b & 7); }
}

// ---------- bf16-MFMA screening: 512 threads, 256 query rows/block ----------
// grid (NCH, 4) = 768 blocks = exactly 3/CU (24 waves/CU), zero tail.
// acc init = -kk/2 -> score = -d/2 (negative; uint order = ascending d). Per-lane
// branchless top-3 of packed (score|11-bit idx); quad butterfly -> top-3 per chunk.
__global__ __launch_bounds__(512, 4)
void screen_topk(const ushort* __restrict__ qbf, const uint4* __restrict__ img,
                 const float* __restrict__ khalf, int* __restrict__ cand_i) {
    __shared__ uint4 buf[2][1024];
    __shared__ float kls[CHK];
    const int tid = threadIdx.x;
    const int wv = tid >> 6, ln = tid & 63;
    const int quad = ln >> 4, l15 = ln & 15;
    const int m0 = blockIdx.y * 256 + wv * 32;
    const int c0 = blockIdx.x * CHK;
    const int t0 = blockIdx.x * TPC;

    bf16x8 afA[4], afB[4];
    {
        const ushort* qa = qbf + (size_t)(m0 + l15) * 128 + quad * 8;
#pragma unroll
        for (int s = 0; s < 4; ++s) {
            afA[s] = *(const bf16x8*)(qa + 32 * s);
            afB[s] = *(const bf16x8*)(qa + 16 * 128 + 32 * s);
        }
    }
    for (int i = tid; i < CHK; i += 512) kls[i] = khalf[c0 + i];

    unsigned mA[4][3], mB[4][3];
#pragma unroll
    for (int r = 0; r < 4; ++r)
#pragma unroll
        for (int p = 0; p < 3; ++p) { mA[r][p] = 0xFFFFFFFFu; mB[r][p] = 0xFFFFFFFFu; }

#pragma unroll
    for (int it = 0; it < 2; ++it)
        gl_lds16(&img[(size_t)t0 * 1024 + it * 512 + wv * 64 + ln],
                 &buf[0][it * 512 + wv * 64]);
    __syncthreads();

    for (int t = 0; t < TPC; ++t) {
        const int b = t & 1;
        if (t + 1 < TPC) {
#pragma unroll
            for (int it = 0; it < 2; ++it)
                gl_lds16(&img[(size_t)(t0 + t + 1) * 1024 + it * 512 + wv * 64 + ln],
                         &buf[b ^ 1][it * 512 + wv * 64]);
        }
#pragma unroll
        for (int ct = 0; ct < 4; ++ct) {
            const int nl = t * 64 + ct * 16 + l15;
            const float kh = kls[nl];
            f32x4 a0 = {kh, kh, kh, kh}, a1 = {kh, kh, kh, kh};
#pragma unroll
            for (int s = 0; s < 4; ++s) {
                bf16x8 bfr = *(const bf16x8*)&buf[b][(ct * 4 + s) * 64 + ln];
                a0 = __builtin_amdgcn_mfma_f32_16x16x32_bf16(afA[s], bfr, a0, 0, 0, 0);
                a1 = __builtin_amdgcn_mfma_f32_16x16x32_bf16(afB[s], bfr, a1, 0, 0, 0);
            }
#pragma unroll
            for (int r = 0; r < 4; ++r) {
                ins3u(mA[r], (__float_as_uint(a0[r]) & 0xFFFFF800u) | (unsigned)nl);
                ins3u(mB[r], (__float_as_uint(a1[r]) & 0xFFFFF800u) | (unsigned)nl);
            }
        }
        __syncthreads();
    }

#pragma unroll
    for (int set = 0; set < 2; ++set) {
#pragma unroll
        for (int r = 0; r < 4; ++r) {
            unsigned m[3];
#pragma unroll
            for (int p = 0; p < 3; ++p) m[p] = set ? mB[r][p] : mA[r][p];
#pragma unroll
            for (int st = 1; st <= 8; st <<= 1) {
                unsigned o[3];
#pragma unroll
                for (int p = 0; p < 3; ++p) o[p] = (unsigned)__shfl_xor((int)m[p], st, 64);
#pragma unroll
                for (int p = 0; p < 3; ++p) ins3u(m, o[p]);
            }
            if (l15 == 0) {
                const int row = m0 + set * 16 + quad * 4 + r;
#pragma unroll
                for (int p = 0; p < 3; ++p)
                    cand_i[((size_t)row * NCH + blockIdx.x) * 3 + p] = c0 + (int)(m[p] & 0x7FFu);
            }
        }
    }
}

// ---------- exact f32 re-rank: quad-per-candidate ----------
__global__ __launch_bounds__(512)
void rerank_gather(const int* __restrict__ cand_i, const float* __restrict__ cq,
                   const float* __restrict__ keysf, const float* __restrict__ qq,
                   const float* __restrict__ kk, const float* __restrict__ values,
                   ushort* __restrict__ wbf, float* __restrict__ conf_out) {
    __shared__ __align__(16) float qs[128];
    __shared__ float ed[NCAND];
    __shared__ int   ei[NCAND];
    __shared__ float w5[5];
    __shared__ int   s5[5];
    __shared__ float confs;
    const int row = blockIdx.x, tid = threadIdx.x;
    const int ln = tid & 63;
    const int qd = tid >> 4;
    const int l15 = tid & 15;
    if (tid < 128) qs[tid] = cq[(size_t)row * 128 + tid];
    for (int c = tid; c < NCAND; c += 512) ei[c] = cand_i[(size_t)row * NCAND + c];
    __syncthreads();
    const float4 qa = *(const float4*)&qs[l15 * 8];
    const float4 qb = *(const float4*)&qs[l15 * 8 + 4];
    const float qqr = qq[row];
#pragma unroll 3
    for (int it = 0; it < (NCAND + 31) / 32; ++it) {
        const int c = qd + it * 32;
        if (c < NCAND) {
            const int idx = ei[c];
            const int idc = idx < NKEYS ? idx : NKEYS - 1;   // pad cands: kk=BIGF kills them
            const float* kp = &keysf[(size_t)idc * 128 + l15 * 8];
            const float4 ka = *(const float4*)kp;
            const float4 kb = *(const float4*)(kp + 4);
            float dot = qa.x * ka.x + qa.y * ka.y + qa.z * ka.z + qa.w * ka.w
                      + qb.x * kb.x + qb.y * kb.y + qb.z * kb.z + qb.w * kb.w;
            dot += __shfl_xor(dot, 1, 64);
            dot += __shfl_xor(dot, 2, 64);
            dot += __shfl_xor(dot, 4, 64);
            dot += __shfl_xor(dot, 8, 64);
            if (l15 == 0) ed[c] = qqr + kk[idx] - 2.0f * dot;
        }
    }
    __syncthreads();
    if (tid < 64) {
        float bd[5]; int bi[5];
#pragma unroll
        for (int p = 0; p < 5; ++p) { bd[p] = BIGF; bi[p] = 0; }
        for (int c = ln; c < NCAND; c += 64) ins5(bd, bi, ed[c], ei[c]);
#pragma unroll
        for (int m = 1; m <= 32; m <<= 1) {
            float od[5]; int oi[5];
#pragma unroll
            for (int p = 0; p < 5; ++p) {
                od[p] = __shfl_xor(bd[p], m, 64);
                oi[p] = __shfl_xor(bi[p], m, 64);
            }
#pragma unroll
            for (int p = 0; p < 5; ++p) ins5(bd, bi, od[p], oi[p]);
        }
        if (ln == 0) {
            float ww[5]; float s = 0.f;
#pragma unroll
            for (int p = 0; p < 5; ++p) { ww[p] = 1.0f / (bd[p] + EPS_F); s += ww[p]; }
#pragma unroll
            for (int p = 0; p < 5; ++p) { w5[p] = ww[p] / s; s5[p] = bi[p]; }
            confs = 1.0f / (bd[0] + EPS_F);
        }
    }
    __syncthreads();
    if (tid < 128) {
        float acc = 0.f;
#pragma unroll
        for (int p = 0; p < 5; ++p) acc += w5[p] * values[(size_t)s5[p] * 128 + tid];
        wbf[(size_t)row * 128 + tid] = bf16bits(acc);
    }
    if (tid == 0) conf_out[row] = confs;
}

// ---------- bf16-MFMA GEMM for decompress MLP: C = act(A@W + b) ----------
template <int RELU, int OUTF32>
__global__ __launch_bounds__(256)
void bgemm_bias(const ushort* __restrict__ Abf, const uint4* __restrict__ Wimg,
                const float* __restrict__ bias, void* __restrict__ Cout,
                int M, int N, int K) {
    __shared__ uint4 pan[2][512];
    const int tid = threadIdx.x;
    const int wv = tid >> 6, ln = tid & 63;
    const int quad = ln >> 4, l15 = ln & 15;
    const int n0 = blockIdx.x * 64;
    const int m0 = blockIdx.y * 128 + wv * 32;
    const int ctile = blockIdx.x, npan = K >> 6;
    f32x4 acc[2][4];
#pragma unroll
    for (int s = 0; s < 2; ++s)
#pragma unroll
        for (int c = 0; c < 4; ++c) acc[s][c] = (f32x4){0.f, 0.f, 0.f, 0.f};

#pragma unroll
    for (int it = 0; it < 2; ++it)
        gl_lds16(&Wimg[(size_t)ctile * npan * 512 + it * 256 + wv * 64 + ln],
                 &pan[0][it * 256 + wv * 64]);
    __syncthreads();

    for (int p = 0; p < npan; ++p) {
        const int b = p & 1;
        if (p + 1 < npan) {
#pragma unroll
            for (int it = 0; it < 2; ++it)
                gl_lds16(&Wimg[((size_t)ctile * npan + p + 1) * 512 + it * 256 + wv * 64 + ln],
                         &pan[b ^ 1][it * 256 + wv * 64]);
        }
        const ushort* arow = Abf + (size_t)(m0 + l15) * K + p * 64 + quad * 8;
        bf16x8 afA[2], afB[2];
#pragma unroll
        for (int s = 0; s < 2; ++s) {
            afA[s] = *(const bf16x8*)(arow + s * 32);
            afB[s] = *(const bf16x8*)(arow + (size_t)16 * K + s * 32);
        }
#pragma unroll
        for (int ct = 0; ct < 4; ++ct)
#pragma unroll
            for (int s = 0; s < 2; ++s) {
                bf16x8 bfr = *(const bf16x8*)&pan[b][((ct * 2 + s) * 4 + quad) * 16 + l15];
                acc[0][ct] = __builtin_amdgcn_mfma_f32_16x16x32_bf16(afA[s], bfr, acc[0][ct], 0, 0, 0);
                acc[1][ct] = __builtin_amdgcn_mfma_f32_16x16x32_bf16(afB[s], bfr, acc[1][ct], 0, 0, 0);
            }
        __syncthreads();
    }

#pragma unroll
    for (int ct = 0; ct < 4; ++ct) {
        const int col = n0 + ct * 16 + l15;
        const float bv = bias[col];
#pragma unroll
        for (int set = 0; set < 2; ++set)
#pragma unroll
            for (int r = 0; r < 4; ++r) {
                float v = acc[set][ct][r] + bv;
                if (RELU) v = fmaxf(v, 0.f);
                const int row = m0 + set * 16 + quad * 4 + r;
                if (OUTF32) ((float*)Cout)[(size_t)row * N + col] = v;
                else        ((ushort*)Cout)[(size_t)row * N + col] = bf16bits(v);
            }
    }
}

extern "C" void kernel_launch(void* const* d_in, const int* in_sizes, int n_in,
                              void* d_out, int out_size, void* d_ws, size_t ws_size,
                              hipStream_t stream) {
    const float* query  = (const float*)d_in[0];
    const float* W1     = (const float*)d_in[1];
    const float* b1     = (const float*)d_in[2];
    const float* W2     = (const float*)d_in[3];
    const float* b2     = (const float*)d_in[4];
    const float* W3     = (const float*)d_in[5];
    const float* b3     = (const float*)d_in[6];
    const float* keys   = (const float*)d_in[7];
    const float* values = (const float*)d_in[8];
    const float* D1w    = (const float*)d_in[9];
    const float* D1b    = (const float*)d_in[10];
    const float* D2w    = (const float*)d_in[11];
    const float* D2b    = (const float*)d_in[12];
    const float* D3w    = (const float*)d_in[13];
    const float* D3b    = (const float*)d_in[14];
    float* out = (float*)d_out;

    // ---- workspace (f32 words), 32.4 MB total ----
    // Persistent: kk, khalf, qq, cq, qbf, cand. Region R (7,077,888 w) is
    // time-multiplexed: compress buffers -> key image -> decompress overlays.
    float*  ws    = (float*)d_ws;
    float*  kk    = ws;                        // 110592
    float*  khalf = ws + 110592;               // 110592
    float*  qq    = ws + 221184;               // 1024
    float*  cq    = ws + 222208;               // 131072
    ushort* qbf   = (ushort*)(ws + 353280);    // 65536 w
    int*    cand  = (int*)(ws + 418816);       // 1024*576 = 589824 w
    float*  R     = ws + 1008640;              // 7,077,888 w
    // compress overlays:
    ushort* xbig  = (ushort*)R;                           // 1572864 w
    uint4*  W1img = (uint4*)(R + 1572864);                // 786432 w
    float*  partA = R + 2359296;                          // 6 x 524288 = 3145728 w
    float*  partB = R + 5505024;                          // 4 x 262144 = 1048576 w
    float*  partC = R + 6553600;                          // 4 x 131072 = 524288 w
    // key image (after compress):
    uint4*  img   = (uint4*)R;                            // 1728 x 1024 uint4 = 7077888 w
    // decompress overlays (after screen):
    ushort* wbf   = (ushort*)R;                           // 65536 w
    ushort* h3bf  = (ushort*)(R + 65536);                 // 131072 w
    ushort* h4bf  = (ushort*)(R + 196608);                // 262144 w
    uint4*  Wimg1 = (uint4*)(R + 458752);                 // 16384 w
    uint4*  Wimg2 = (uint4*)(R + 475136);                 // 65536 w
    uint4*  Wimg3 = (uint4*)(R + 540672);                 // 262144 w
    float*  conf  = out + 1024 * 1024;

    // compress MLP: L1 split-bf16 MFMA (z=6), L2/L3 f32 split-K with fused
    // A-side partial-reduce+bias+relu; final layer fuses reduce+rowsq+cvt.
    prep<<<1408, 256, 0, stream>>>(query, xbig, W1, W1img);
    bgemm_part<<<dim3(8, 8, 6), 256, 0, stream>>>(xbig, W1img, partA, 1024, 512, 3072, 8);
    sgemm_part<6><<<dim3(4, 16, 4), 256, 0, stream>>>(partA, b1, W2, partB, 1024, 256, 512, 128, 1024 * 512);
    sgemm_part<4><<<dim3(2, 16, 4), 256, 0, stream>>>(partB, b2, W3, partC, 1024, 128, 256, 64, 1024 * 256);
    final_row<<<1024, 128, 0, stream>>>(partC, b3, cq, qbf, qq);
    // retrieval
    cvt_keys<<<NTILE, 256, 0, stream>>>(keys, img, kk, khalf);
    screen_topk<<<dim3(NCH, BQ / 256), 512, 0, stream>>>(qbf, img, khalf, cand);
    rerank_gather<<<BQ, 512, 0, stream>>>(cand, cq, keys, qq, kk, values, wbf, conf);
    // decompress MLP (bf16 MFMA)
    cvt_wT_all<<<168, 256, 0, stream>>>(D1w, D2w, D3w, Wimg1, Wimg2, Wimg3);
    bgemm_bias<1, 0><<<dim3(4, 8),  256, 0, stream>>>(wbf,  Wimg1, D1b, h3bf, 1024, 256,  128);
    bgemm_bias<1, 0><<<dim3(8, 8),  256, 0, stream>>>(h3bf, Wimg2, D2b, h4bf, 1024, 512,  256);
    bgemm_bias<0, 1><<<dim3(16, 8), 256, 0, stream>>>(h4bf, Wimg3, D3b, out,  1024, 1024, 512);

    (void)in_sizes; (void)n_in; (void)out_size; (void)ws_size;
}

// Round 10
// 283.314 us; speedup vs baseline: 1.0417x; 1.0417x over previous
//
#include <hip/hip_runtime.h>
#include <hip/hip_bf16.h>

#define NKEYS  100000
#define NCH    128
#define CHK    832             // 13 tiles of 64 keys  (r8 proven screen config)
#define TPC    13
#define KPAD   (NCH * CHK)     // 106496
#define NTILE  (KPAD / 64)     // 1664
#define BQ     1024
#define EPS_F  1e-6f
#define NCAND  (NCH * 3)       // 384 candidates per row
#define BIGF   1e30f

typedef __attribute__((ext_vector_type(8))) short bf16x8;
typedef __attribute__((ext_vector_type(4))) float f32x4;

__device__ __forceinline__ void gl_lds16(const uint4* g, uint4* l) {
    __builtin_amdgcn_global_load_lds((const __attribute__((address_space(1))) void*)g,
                                     (__attribute__((address_space(3))) void*)l, 16, 0, 0);
}
__device__ __forceinline__ unsigned umn(unsigned a, unsigned b) { return a < b ? a : b; }
__device__ __forceinline__ unsigned umx(unsigned a, unsigned b) { return a > b ? a : b; }
__device__ __forceinline__ ushort bf16bits(float v) {
    __hip_bfloat16 h = __float2bfloat16(v);
    return *(ushort*)&h;
}

__device__ __forceinline__ void ins3u(unsigned (&m)[3], unsigned u) {
    unsigned v1 = umn(m[2], u);
    m[2] = umx(m[1], v1);
    unsigned v2 = umn(m[1], v1);
    m[1] = umx(m[0], v2);
    m[0] = umn(m[0], v2);
}

__device__ __forceinline__ void ins5(float (&d)[5], int (&ix)[5], float nd, int ni) {
    if (nd < d[4]) {
        d[4] = nd; ix[4] = ni;
#pragma unroll
        for (int p = 4; p > 0; --p) {
            if (d[p] < d[p - 1]) {
                float td = d[p]; d[p] = d[p - 1]; d[p - 1] = td;
                int   ti = ix[p]; ix[p] = ix[p - 1]; ix[p - 1] = ti;
            }
        }
    }
}

// ---------- fragment-major bf16 weight panel (shared by key/weight converters) ----------
__device__ __forceinline__ void wT_panel(const float* __restrict__ W, uint4* __restrict__ Wimg,
                                         int K, int N, int ctile, int p) {
    const int npan = K >> 6;
#pragma unroll
    for (int it = 0; it < 2; ++it) {
        int c = it * 256 + threadIdx.x;
        int l15 = c & 15, quad = (c >> 4) & 3, s = (c >> 6) & 1, ct = c >> 7;
        int n = ctile * 64 + ct * 16 + l15;
        int k = p * 64 + s * 32 + quad * 8;
        ushort h[8];
#pragma unroll
        for (int j = 0; j < 8; ++j) h[j] = bf16bits(W[(size_t)(k + j) * N + n]);
        Wimg[((size_t)ctile * npan + p) * 512 + c] =
            make_uint4((uint)h[0] | ((uint)h[1] << 16), (uint)h[2] | ((uint)h[3] << 16),
                       (uint)h[4] | ((uint)h[5] << 16), (uint)h[6] | ((uint)h[7] << 16));
    }
}

// ---------- fused: key image + kk/khalf (blocks < NTILE) + decompress weight images ----------
__global__ __launch_bounds__(256)
void cvt_keys_w(const float* __restrict__ keys, uint4* __restrict__ img,
                float* __restrict__ kk, float* __restrict__ khalf,
                const float* __restrict__ D1w, const float* __restrict__ D2w,
                const float* __restrict__ D3w, uint4* __restrict__ I1,
                uint4* __restrict__ I2, uint4* __restrict__ I3) {
    if (blockIdx.x >= NTILE) {
        int b = blockIdx.x - NTILE;  // 0..167
        if (b < 8)       { wT_panel(D1w, I1, 128, 256,  b >> 1, b & 1); }
        else if (b < 40) { b -= 8;  wT_panel(D2w, I2, 256, 512,  b >> 2, b & 3); }
        else             { b -= 40; wT_panel(D3w, I3, 512, 1024, b >> 3, b & 7); }
        return;
    }
    const int tid = threadIdx.x;
    const int r = tid >> 2, s = tid & 3;
    const int tile = blockIdx.x;
    const int n = tile * 64 + r;
    const int ct = r >> 4, l15 = r & 15;
    const bool live = (n < NKEYS);
    const float* kp = keys + (size_t)n * 128 + s * 32;
    float ss = 0.f;
    uint4 out[4];
#pragma unroll
    for (int q = 0; q < 4; ++q) {
        float4 a = make_float4(0.f, 0.f, 0.f, 0.f), b = a;
        if (live) { a = *(const float4*)(kp + q * 8); b = *(const float4*)(kp + q * 8 + 4); }
        ss += a.x * a.x + a.y * a.y + a.z * a.z + a.w * a.w
            + b.x * b.x + b.y * b.y + b.z * b.z + b.w * b.w;
        float v[8] = {a.x, a.y, a.z, a.w, b.x, b.y, b.z, b.w};
        ushort h[8];
#pragma unroll
        for (int j = 0; j < 8; ++j) h[j] = bf16bits(v[j]);
        out[q] = make_uint4((uint)h[0] | ((uint)h[1] << 16), (uint)h[2] | ((uint)h[3] << 16),
                            (uint)h[4] | ((uint)h[5] << 16), (uint)h[6] | ((uint)h[7] << 16));
    }
    ss += __shfl_xor(ss, 1, 64);
    ss += __shfl_xor(ss, 2, 64);
    if (s == 0) {
        kk[n]    = live ? ss : BIGF;
        khalf[n] = live ? -0.5f * ss : -BIGF;
    }
#pragma unroll
    for (int q = 0; q < 4; ++q)
        img[(size_t)tile * 1024 + ((ct * 4 + s) * 4 + q) * 16 + l15] = out[q];
}

// ---------- fused compress prep: query split-A (blocks 0..1023) + W1 K-tripled image ----------
__global__ __launch_bounds__(256)
void prep(const float* __restrict__ A, ushort* __restrict__ Ax,
          const float* __restrict__ W, uint4* __restrict__ Wimg) {
    const int b = blockIdx.x;
    if (b < 1024) {
        const int row = b;
        const int i = threadIdx.x * 4;
        float4 v = *(const float4*)&A[(size_t)row * 1024 + i];
        float x[4] = {v.x, v.y, v.z, v.w};
        ushort h[4], l[4];
#pragma unroll
        for (int j = 0; j < 4; ++j) {
            __hip_bfloat16 hb = __float2bfloat16(x[j]);
            h[j] = *(ushort*)&hb;
            l[j] = bf16bits(x[j] - __bfloat162float(hb));
        }
        ushort* o = Ax + (size_t)row * 3072;
        *(ushort4*)&o[i]        = make_ushort4(h[0], h[1], h[2], h[3]);
        *(ushort4*)&o[1024 + i] = make_ushort4(l[0], l[1], l[2], l[3]);
        *(ushort4*)&o[2048 + i] = make_ushort4(h[0], h[1], h[2], h[3]);
    } else {
        const int idx = b - 1024;          // 0..383
        const int ctile = idx / 48, p = idx % 48;
        const int part = p >> 4, psrc = p & 15;
#pragma unroll
        for (int it = 0; it < 2; ++it) {
            int c = it * 256 + threadIdx.x;
            int l15 = c & 15, quad = (c >> 4) & 3, s = (c >> 6) & 1, ct = c >> 7;
            int n = ctile * 64 + ct * 16 + l15;
            int k = psrc * 64 + s * 32 + quad * 8;
            ushort h[8];
#pragma unroll
            for (int j = 0; j < 8; ++j) {
                float w = W[(size_t)(k + j) * 512 + n];
                __hip_bfloat16 hb = __float2bfloat16(w);
                if (part < 2) h[j] = *(ushort*)&hb;
                else h[j] = bf16bits(w - __bfloat162float(hb));
            }
            Wimg[((size_t)ctile * 48 + p) * 512 + c] =
                make_uint4((uint)h[0] | ((uint)h[1] << 16), (uint)h[2] | ((uint)h[3] << 16),
                           (uint)h[4] | ((uint)h[5] << 16), (uint)h[6] | ((uint)h[7] << 16));
        }
    }
}

// ---------- bf16-MFMA split-K partial GEMM: P[z] = A@W over panel slab ----------
__global__ __launch_bounds__(256)
void bgemm_part(const ushort* __restrict__ Abf, const uint4* __restrict__ Wimg,
                float* __restrict__ P, int M, int N, int K, int ppz) {
    __shared__ uint4 pan[2][512];
    const int tid = threadIdx.x;
    const int wv = tid >> 6, ln = tid & 63;
    const int quad = ln >> 4, l15 = ln & 15;
    const int n0 = blockIdx.x * 64;
    const int m0 = blockIdx.y * 128 + wv * 32;
    const int ctile = blockIdx.x, npanT = K >> 6;
    const int p0 = blockIdx.z * ppz;
    f32x4 acc[2][4];
#pragma unroll
    for (int s = 0; s < 2; ++s)
#pragma unroll
        for (int c = 0; c < 4; ++c) acc[s][c] = (f32x4){0.f, 0.f, 0.f, 0.f};

#pragma unroll
    for (int it = 0; it < 2; ++it)
        gl_lds16(&Wimg[((size_t)ctile * npanT + p0) * 512 + it * 256 + wv * 64 + ln],
                 &pan[0][it * 256 + wv * 64]);
    __syncthreads();

    for (int pp = 0; pp < ppz; ++pp) {
        const int p = p0 + pp;
        const int b = pp & 1;
        if (pp + 1 < ppz) {
#pragma unroll
            for (int it = 0; it < 2; ++it)
                gl_lds16(&Wimg[((size_t)ctile * npanT + p + 1) * 512 + it * 256 + wv * 64 + ln],
                         &pan[b ^ 1][it * 256 + wv * 64]);
        }
        const ushort* arow = Abf + (size_t)(m0 + l15) * K + p * 64 + quad * 8;
        bf16x8 afA[2], afB[2];
#pragma unroll
        for (int s = 0; s < 2; ++s) {
            afA[s] = *(const bf16x8*)(arow + s * 32);
            afB[s] = *(const bf16x8*)(arow + (size_t)16 * K + s * 32);
        }
#pragma unroll
        for (int ct = 0; ct < 4; ++ct)
#pragma unroll
            for (int s = 0; s < 2; ++s) {
                bf16x8 bfr = *(const bf16x8*)&pan[b][((ct * 2 + s) * 4 + quad) * 16 + l15];
                acc[0][ct] = __builtin_amdgcn_mfma_f32_16x16x32_bf16(afA[s], bfr, acc[0][ct], 0, 0, 0);
                acc[1][ct] = __builtin_amdgcn_mfma_f32_16x16x32_bf16(afB[s], bfr, acc[1][ct], 0, 0, 0);
            }
        __syncthreads();
    }

    P += (size_t)blockIdx.z * M * N;
#pragma unroll
    for (int ct = 0; ct < 4; ++ct) {
        const int col = n0 + ct * 16 + l15;
#pragma unroll
        for (int set = 0; set < 2; ++set)
#pragma unroll
            for (int r = 0; r < 4; ++r)
                P[(size_t)(m0 + set * 16 + quad * 4 + r) * N + col] = acc[set][ct][r];
    }
}

// ---------- split-K f32 GEMM; A-side fuses NP-partial reduce+bias+relu ----------
template <int NP>
__global__ __launch_bounds__(256)
void sgemm_part(const float* __restrict__ A, const float* __restrict__ abias,
                const float* __restrict__ W, float* __restrict__ P,
                int M, int N, int K, int kslice, int MNpart) {
    __shared__ float As[16][68];
    __shared__ float Bs[16][64];
    const int tid = threadIdx.x;
    const int tx = tid & 15, ty = tid >> 4;
    const int m0 = blockIdx.y * 64, n0 = blockIdx.x * 64;
    const int kb = blockIdx.z * kslice, ke = kb + kslice;
    float acc[4][4] = {};
    for (int k0 = kb; k0 < ke; k0 += 16) {
        {
            int m = tid >> 2, k4 = (tid & 3) * 4;
            const float* ap = &A[(size_t)(m0 + m) * K + k0 + k4];
            float4 a = *(const float4*)ap;
            if (NP > 0) {
#pragma unroll
                for (int z = 1; z < NP; ++z) {
                    float4 v = *(const float4*)(ap + (size_t)z * MNpart);
                    a.x += v.x; a.y += v.y; a.z += v.z; a.w += v.w;
                }
                float4 b = *(const float4*)&abias[k0 + k4];
                a.x = fmaxf(a.x + b.x, 0.f); a.y = fmaxf(a.y + b.y, 0.f);
                a.z = fmaxf(a.z + b.z, 0.f); a.w = fmaxf(a.w + b.w, 0.f);
            }
            As[k4 + 0][m] = a.x; As[k4 + 1][m] = a.y;
            As[k4 + 2][m] = a.z; As[k4 + 3][m] = a.w;
        }
        {
            int k = tid >> 4, n4 = (tid & 15) * 4;
            *(float4*)&Bs[k][n4] = *(const float4*)&W[(size_t)(k0 + k) * N + n0 + n4];
        }
        __syncthreads();
#pragma unroll
        for (int kkk = 0; kkk < 16; ++kkk) {
            float4 a4 = *(const float4*)&As[kkk][ty * 4];
            float4 b4 = *(const float4*)&Bs[kkk][tx * 4];
            float av[4] = {a4.x, a4.y, a4.z, a4.w};
            float bv[4] = {b4.x, b4.y, b4.z, b4.w};
#pragma unroll
            for (int i = 0; i < 4; ++i)
#pragma unroll
                for (int j = 0; j < 4; ++j)
                    acc[i][j] = fmaf(av[i], bv[j], acc[i][j]);
        }
        __syncthreads();
    }
    P += (size_t)blockIdx.z * M * N;
#pragma unroll
    for (int i = 0; i < 4; ++i)
        *(float4*)&P[(size_t)(m0 + ty * 4 + i) * N + n0 + tx * 4] =
            make_float4(acc[i][0], acc[i][1], acc[i][2], acc[i][3]);
}

// ---------- fused compress layer 3: partB(4) -> h2 -> cq/qbf/qq (one row/block) ----------
__global__ __launch_bounds__(128)
void layer3_full(const float* __restrict__ partB, const float* __restrict__ b2,
                 const float* __restrict__ W3, const float* __restrict__ b3,
                 float* __restrict__ cq, ushort* __restrict__ qbf,
                 float* __restrict__ qq) {
    __shared__ float h2s[256];
    __shared__ float red[2];
    const int row = blockIdx.x, c = threadIdx.x;
#pragma unroll
    for (int u = 0; u < 2; ++u) {
        const int k = c + u * 128;
        float v = 0.f;
#pragma unroll
        for (int z = 0; z < 4; ++z) v += partB[(size_t)z * (BQ * 256) + row * 256 + k];
        h2s[k] = fmaxf(v + b2[k], 0.f);
    }
    __syncthreads();
    float a0 = 0.f, a1 = 0.f, a2 = 0.f, a3 = 0.f;
#pragma unroll 4
    for (int k = 0; k < 256; k += 4) {
        a0 = fmaf(h2s[k + 0], W3[(size_t)(k + 0) * 128 + c], a0);
        a1 = fmaf(h2s[k + 1], W3[(size_t)(k + 1) * 128 + c], a1);
        a2 = fmaf(h2s[k + 2], W3[(size_t)(k + 2) * 128 + c], a2);
        a3 = fmaf(h2s[k + 3], W3[(size_t)(k + 3) * 128 + c], a3);
    }
    const float out = (a0 + a1) + (a2 + a3) + b3[c];
    cq[(size_t)row * 128 + c] = out;
    qbf[(size_t)row * 128 + c] = bf16bits(out);
    float s = out * out;
#pragma unroll
    for (int off = 32; off > 0; off >>= 1) s += __shfl_down(s, off, 64);
    if ((c & 63) == 0) red[c >> 6] = s;
    __syncthreads();
    if (c == 0) qq[row] = red[0] + red[1];
}

// ---------- bf16-MFMA screening (r8 proven: 512 thr, 256 rows/block, grid (128,4)) ----------
__global__ __launch_bounds__(512, 4)
void screen_topk(const ushort* __restrict__ qbf, const uint4* __restrict__ img,
                 const float* __restrict__ khalf, int* __restrict__ cand_i) {
    __shared__ uint4 buf[2][1024];
    __shared__ float kls[CHK];
    const int tid = threadIdx.x;
    const int wv = tid >> 6, ln = tid & 63;
    const int quad = ln >> 4, l15 = ln & 15;
    const int m0 = blockIdx.y * 256 + wv * 32;
    const int c0 = blockIdx.x * CHK;
    const int t0 = blockIdx.x * TPC;

    bf16x8 afA[4], afB[4];
    {
        const ushort* qa = qbf + (size_t)(m0 + l15) * 128 + quad * 8;
#pragma unroll
        for (int s = 0; s < 4; ++s) {
            afA[s] = *(const bf16x8*)(qa + 32 * s);
            afB[s] = *(const bf16x8*)(qa + 16 * 128 + 32 * s);
        }
    }
    for (int i = tid; i < CHK; i += 512) kls[i] = khalf[c0 + i];

    unsigned mA[4][3], mB[4][3];
#pragma unroll
    for (int r = 0; r < 4; ++r)
#pragma unroll
        for (int p = 0; p < 3; ++p) { mA[r][p] = 0xFFFFFFFFu; mB[r][p] = 0xFFFFFFFFu; }

#pragma unroll
    for (int it = 0; it < 2; ++it)
        gl_lds16(&img[(size_t)t0 * 1024 + it * 512 + wv * 64 + ln],
                 &buf[0][it * 512 + wv * 64]);
    __syncthreads();

    for (int t = 0; t < TPC; ++t) {
        const int b = t & 1;
        if (t + 1 < TPC) {
#pragma unroll
            for (int it = 0; it < 2; ++it)
                gl_lds16(&img[(size_t)(t0 + t + 1) * 1024 + it * 512 + wv * 64 + ln],
                         &buf[b ^ 1][it * 512 + wv * 64]);
        }
#pragma unroll
        for (int ct = 0; ct < 4; ++ct) {
            const int nl = t * 64 + ct * 16 + l15;
            const float kh = kls[nl];
            f32x4 a0 = {kh, kh, kh, kh}, a1 = {kh, kh, kh, kh};
#pragma unroll
            for (int s = 0; s < 4; ++s) {
                bf16x8 bfr = *(const bf16x8*)&buf[b][(ct * 4 + s) * 64 + ln];
                a0 = __builtin_amdgcn_mfma_f32_16x16x32_bf16(afA[s], bfr, a0, 0, 0, 0);
                a1 = __builtin_amdgcn_mfma_f32_16x16x32_bf16(afB[s], bfr, a1, 0, 0, 0);
            }
#pragma unroll
            for (int r = 0; r < 4; ++r) {
                ins3u(mA[r], (__float_as_uint(a0[r]) & 0xFFFFF800u) | (unsigned)nl);
                ins3u(mB[r], (__float_as_uint(a1[r]) & 0xFFFFF800u) | (unsigned)nl);
            }
        }
        __syncthreads();
    }

#pragma unroll
    for (int set = 0; set < 2; ++set) {
#pragma unroll
        for (int r = 0; r < 4; ++r) {
            unsigned m[3];
#pragma unroll
            for (int p = 0; p < 3; ++p) m[p] = set ? mB[r][p] : mA[r][p];
#pragma unroll
            for (int st = 1; st <= 8; st <<= 1) {
                unsigned o[3];
#pragma unroll
                for (int p = 0; p < 3; ++p) o[p] = (unsigned)__shfl_xor((int)m[p], st, 64);
#pragma unroll
                for (int p = 0; p < 3; ++p) ins3u(m, o[p]);
            }
            if (l15 == 0) {
                const int row = m0 + set * 16 + quad * 4 + r;
#pragma unroll
                for (int p = 0; p < 3; ++p)
                    cand_i[((size_t)row * NCH + blockIdx.x) * 3 + p] = c0 + (int)(m[p] & 0x7FFu);
            }
        }
    }
}

// ---------- exact f32 re-rank: quad-per-candidate ----------
__global__ __launch_bounds__(512)
void rerank_gather(const int* __restrict__ cand_i, const float* __restrict__ cq,
                   const float* __restrict__ keysf, const float* __restrict__ qq,
                   const float* __restrict__ kk, const float* __restrict__ values,
                   ushort* __restrict__ wbf, float* __restrict__ conf_out) {
    __shared__ __align__(16) float qs[128];
    __shared__ float ed[NCAND];
    __shared__ int   ei[NCAND];
    __shared__ float w5[5];
    __shared__ int   s5[5];
    __shared__ float confs;
    const int row = blockIdx.x, tid = threadIdx.x;
    const int ln = tid & 63;
    const int qd = tid >> 4;
    const int l15 = tid & 15;
    if (tid < 128) qs[tid] = cq[(size_t)row * 128 + tid];
    for (int c = tid; c < NCAND; c += 512) ei[c] = cand_i[(size_t)row * NCAND + c];
    __syncthreads();
    const float4 qa = *(const float4*)&qs[l15 * 8];
    const float4 qb = *(const float4*)&qs[l15 * 8 + 4];
    const float qqr = qq[row];
#pragma unroll 3
    for (int it = 0; it < (NCAND + 31) / 32; ++it) {
        const int c = qd + it * 32;
        if (c < NCAND) {
            const int idx = ei[c];
            const int idc = idx < NKEYS ? idx : NKEYS - 1;   // pad cands: kk=BIGF kills them
            const float* kp = &keysf[(size_t)idc * 128 + l15 * 8];
            const float4 ka = *(const float4*)kp;
            const float4 kb = *(const float4*)(kp + 4);
            float dot = qa.x * ka.x + qa.y * ka.y + qa.z * ka.z + qa.w * ka.w
                      + qb.x * kb.x + qb.y * kb.y + qb.z * kb.z + qb.w * kb.w;
            dot += __shfl_xor(dot, 1, 64);
            dot += __shfl_xor(dot, 2, 64);
            dot += __shfl_xor(dot, 4, 64);
            dot += __shfl_xor(dot, 8, 64);
            if (l15 == 0) ed[c] = qqr + kk[idx] - 2.0f * dot;
        }
    }
    __syncthreads();
    if (tid < 64) {
        float bd[5]; int bi[5];
#pragma unroll
        for (int p = 0; p < 5; ++p) { bd[p] = BIGF; bi[p] = 0; }
        for (int c = ln; c < NCAND; c += 64) ins5(bd, bi, ed[c], ei[c]);
#pragma unroll
        for (int m = 1; m <= 32; m <<= 1) {
            float od[5]; int oi[5];
#pragma unroll
            for (int p = 0; p < 5; ++p) {
                od[p] = __shfl_xor(bd[p], m, 64);
                oi[p] = __shfl_xor(bi[p], m, 64);
            }
#pragma unroll
            for (int p = 0; p < 5; ++p) ins5(bd, bi, od[p], oi[p]);
        }
        if (ln == 0) {
            float ww[5]; float s = 0.f;
#pragma unroll
            for (int p = 0; p < 5; ++p) { ww[p] = 1.0f / (bd[p] + EPS_F); s += ww[p]; }
#pragma unroll
            for (int p = 0; p < 5; ++p) { w5[p] = ww[p] / s; s5[p] = bi[p]; }
            confs = 1.0f / (bd[0] + EPS_F);
        }
    }
    __syncthreads();
    if (tid < 128) {
        float acc = 0.f;
#pragma unroll
        for (int p = 0; p < 5; ++p) acc += w5[p] * values[(size_t)s5[p] * 128 + tid];
        wbf[(size_t)row * 128 + tid] = bf16bits(acc);
    }
    if (tid == 0) conf_out[row] = confs;
}

// ---------- bf16-MFMA GEMM for decompress MLP: C = act(A@W + b) ----------
template <int RELU, int OUTF32>
__global__ __launch_bounds__(256)
void bgemm_bias(const ushort* __restrict__ Abf, const uint4* __restrict__ Wimg,
                const float* __restrict__ bias, void* __restrict__ Cout,
                int M, int N, int K) {
    __shared__ uint4 pan[2][512];
    const int tid = threadIdx.x;
    const int wv = tid >> 6, ln = tid & 63;
    const int quad = ln >> 4, l15 = ln & 15;
    const int n0 = blockIdx.x * 64;
    const int m0 = blockIdx.y * 128 + wv * 32;
    const int ctile = blockIdx.x, npan = K >> 6;
    f32x4 acc[2][4];
#pragma unroll
    for (int s = 0; s < 2; ++s)
#pragma unroll
        for (int c = 0; c < 4; ++c) acc[s][c] = (f32x4){0.f, 0.f, 0.f, 0.f};

#pragma unroll
    for (int it = 0; it < 2; ++it)
        gl_lds16(&Wimg[(size_t)ctile * npan * 512 + it * 256 + wv * 64 + ln],
                 &pan[0][it * 256 + wv * 64]);
    __syncthreads();

    for (int p = 0; p < npan; ++p) {
        const int b = p & 1;
        if (p + 1 < npan) {
#pragma unroll
            for (int it = 0; it < 2; ++it)
                gl_lds16(&Wimg[((size_t)ctile * npan + p + 1) * 512 + it * 256 + wv * 64 + ln],
                         &pan[b ^ 1][it * 256 + wv * 64]);
        }
        const ushort* arow = Abf + (size_t)(m0 + l15) * K + p * 64 + quad * 8;
        bf16x8 afA[2], afB[2];
#pragma unroll
        for (int s = 0; s < 2; ++s) {
            afA[s] = *(const bf16x8*)(arow + s * 32);
            afB[s] = *(const bf16x8*)(arow + (size_t)16 * K + s * 32);
        }
#pragma unroll
        for (int ct = 0; ct < 4; ++ct)
#pragma unroll
            for (int s = 0; s < 2; ++s) {
                bf16x8 bfr = *(const bf16x8*)&pan[b][((ct * 2 + s) * 4 + quad) * 16 + l15];
                acc[0][ct] = __builtin_amdgcn_mfma_f32_16x16x32_bf16(afA[s], bfr, acc[0][ct], 0, 0, 0);
                acc[1][ct] = __builtin_amdgcn_mfma_f32_16x16x32_bf16(afB[s], bfr, acc[1][ct], 0, 0, 0);
            }
        __syncthreads();
    }

#pragma unroll
    for (int ct = 0; ct < 4; ++ct) {
        const int col = n0 + ct * 16 + l15;
        const float bv = bias[col];
#pragma unroll
        for (int set = 0; set < 2; ++set)
#pragma unroll
            for (int r = 0; r < 4; ++r) {
                float v = acc[set][ct][r] + bv;
                if (RELU) v = fmaxf(v, 0.f);
                const int row = m0 + set * 16 + quad * 4 + r;
                if (OUTF32) ((float*)Cout)[(size_t)row * N + col] = v;
                else        ((ushort*)Cout)[(size_t)row * N + col] = bf16bits(v);
            }
    }
}

extern "C" void kernel_launch(void* const* d_in, const int* in_sizes, int n_in,
                              void* d_out, int out_size, void* d_ws, size_t ws_size,
                              hipStream_t stream) {
    const float* query  = (const float*)d_in[0];
    const float* W1     = (const float*)d_in[1];
    const float* b1     = (const float*)d_in[2];
    const float* W2     = (const float*)d_in[3];
    const float* b2     = (const float*)d_in[4];
    const float* W3     = (const float*)d_in[5];
    const float* b3     = (const float*)d_in[6];
    const float* keys   = (const float*)d_in[7];
    const float* values = (const float*)d_in[8];
    const float* D1w    = (const float*)d_in[9];
    const float* D1b    = (const float*)d_in[10];
    const float* D2w    = (const float*)d_in[11];
    const float* D2b    = (const float*)d_in[12];
    const float* D3w    = (const float*)d_in[13];
    const float* D3b    = (const float*)d_in[14];
    float* out = (float*)d_out;

    // ---- workspace (f32 words), 31.9 MB total ----
    // Persistent: kk, khalf, qq, cq, qbf, cand, Wimg1-3.  Region R (6,815,744 w)
    // time-multiplexed: compress buffers -> key image -> rerank/decompress acts.
    float*  ws    = (float*)d_ws;
    float*  kk    = ws;                        // 106496
    float*  khalf = ws + 106496;               // 106496
    float*  qq    = ws + 212992;               // 1024
    float*  cq    = ws + 214016;               // 131072
    ushort* qbf   = (ushort*)(ws + 345088);    // 65536 w
    int*    cand  = (int*)(ws + 410624);       // 1024*384 = 393216 w
    uint4*  Wimg1 = (uint4*)(ws + 803840);     // 16384 w
    uint4*  Wimg2 = (uint4*)(ws + 820224);     // 65536 w
    uint4*  Wimg3 = (uint4*)(ws + 885760);     // 262144 w
    float*  R     = ws + 1147904;              // 6,815,744 w
    // compress overlays (dead once cvt_keys_w writes img):
    ushort* xbig  = (ushort*)R;                           // 1572864 w
    uint4*  W1img = (uint4*)(R + 1572864);                // 786432 w
    float*  partA = R + 2359296;                          // 6 x 524288 = 3145728 w
    float*  partB = R + 5505024;                          // 4 x 262144 = 1048576 w
    // key image (after compress):
    uint4*  img   = (uint4*)R;                            // 1664 x 1024 uint4
    // post-screen overlays:
    ushort* wbf   = (ushort*)R;                           // 65536 w
    ushort* h3bf  = (ushort*)(R + 65536);                 // 131072 w
    ushort* h4bf  = (ushort*)(R + 196608);                // 262144 w
    float*  conf  = out + 1024 * 1024;

    // compress MLP: L1 split-bf16 MFMA (z=6), L2 f32 split-K (fused A-reduce),
    // L3 fused single kernel -> cq/qbf/qq
    prep<<<1408, 256, 0, stream>>>(query, xbig, W1, W1img);
    bgemm_part<<<dim3(8, 8, 6), 256, 0, stream>>>(xbig, W1img, partA, 1024, 512, 3072, 8);
    sgemm_part<6><<<dim3(4, 16, 4), 256, 0, stream>>>(partA, b1, W2, partB, 1024, 256, 512, 128, 1024 * 512);
    layer3_full<<<1024, 128, 0, stream>>>(partB, b2, W3, b3, cq, qbf, qq);
    // retrieval (key image + decompress weight images in one dispatch)
    cvt_keys_w<<<NTILE + 168, 256, 0, stream>>>(keys, img, kk, khalf,
                                                D1w, D2w, D3w, Wimg1, Wimg2, Wimg3);
    screen_topk<<<dim3(NCH, BQ / 256), 512, 0, stream>>>(qbf, img, khalf, cand);
    rerank_gather<<<BQ, 512, 0, stream>>>(cand, cq, keys, qq, kk, values, wbf, conf);
    // decompress MLP (bf16 MFMA)
    bgemm_bias<1, 0><<<dim3(4, 8),  256, 0, stream>>>(wbf,  Wimg1, D1b, h3bf, 1024, 256,  128);
    bgemm_bias<1, 0><<<dim3(8, 8),  256, 0, stream>>>(h3bf, Wimg2, D2b, h4bf, 1024, 512,  256);
    bgemm_bias<0, 1><<<dim3(16, 8), 256, 0, stream>>>(h4bf, Wimg3, D3b, out,  1024, 1024, 512);

    (void)in_sizes; (void)n_in; (void)out_size; (void)ws_size;
}